// Round 1
// baseline (95.270 us; speedup 1.0000x reference)
//
#include <hip/hip_runtime.h>

#define NB 4096
#define NF 1024
#define NR 64
#define NK 32
#define ND 16
#define BT 8    // b-rows per block
#define RT 32   // r's per block
#define HALF_D_LOG2PI 14.702988531274762f   // 0.5 * 16 * 1.8378770664093453

// ---------------- Phase A: precompute inv_scale, -mean*inv_scale, const ----
__global__ __launch_bounds__(256) void prep_kernel(
    const float* __restrict__ means, const float* __restrict__ scales,
    float* __restrict__ isv, float* __restrict__ nmv, float* __restrict__ cv)
{
    int p = blockIdx.x * 256 + threadIdx.x;   // (r,k) pair index
    if (p >= NR * NK) return;
    const float4* m4 = (const float4*)(means + p * ND);
    const float4* s4 = (const float4*)(scales + p * ND);
    float4* i4 = (float4*)(isv + p * ND);
    float4* n4 = (float4*)(nmv + p * ND);
    float ld = 0.f;
#pragma unroll
    for (int q = 0; q < 4; ++q) {
        float4 m = m4[q], s = s4[q];
        float4 iv, nv;
        iv.x = 1.f / s.x; iv.y = 1.f / s.y; iv.z = 1.f / s.z; iv.w = 1.f / s.w;
        nv.x = -m.x * iv.x; nv.y = -m.y * iv.y; nv.z = -m.z * iv.z; nv.w = -m.w * iv.w;
        ld += logf(s.x) + logf(s.y) + logf(s.z) + logf(s.w);
        i4[q] = iv; n4[q] = nv;
    }
    cv[p] = -ld - HALF_D_LOG2PI;
}

// ---------------- Phase B: main kernel -------------------------------------
__global__ __launch_bounds__(256) void GaussianLayer_64003602645438_kernel(
    const float* __restrict__ x,
    const int* __restrict__ regions,
    const float* __restrict__ isv,
    const float* __restrict__ nmv,
    const float* __restrict__ cv,
    float* __restrict__ out)
{
    __shared__ float xs[BT][NF];        // 32 KB: staged x rows
    __shared__ float xg[BT][RT][ND];    // 16 KB: gathered x (contiguous d)
    __shared__ int   ridx[RT * ND];     // 2 KB: region indices slice

    const int t  = threadIdx.x;
    const int b0 = blockIdx.x * BT;
    const int r0 = blockIdx.y * RT;

    // load region indices for this r-slice
    for (int j = t; j < RT * ND; j += 256)
        ridx[j] = regions[r0 * ND + j];

    // stage x rows (coalesced float4)
    {
        const float4* xsrc = (const float4*)(x + (size_t)b0 * NF);
        float4* xdst = (float4*)(&xs[0][0]);
#pragma unroll
        for (int j = t; j < BT * NF / 4; j += 256)
            xdst[j] = xsrc[j];
    }
    __syncthreads();

    // gather x[b][reg[r][d]] -> xg[b][r][d]   (BT*RT*ND = 4096 elems)
    for (int j = t; j < BT * RT * ND; j += 256) {
        int d  = j & (ND - 1);
        int rl = (j >> 4) & (RT - 1);
        int b  = j >> 9;               // j / (RT*ND)
        xg[b][rl][d] = xs[b][ridx[rl * ND + d]];
    }
    __syncthreads();

    const int k   = t & 31;
    const int rl8 = t >> 5;            // 0..7

#pragma unroll
    for (int it = 0; it < RT / 8; ++it) {
        const int rl = it * 8 + rl8;
        const int r  = r0 + rl;
        const int pk = r * NK + k;
        const float4* i4 = (const float4*)(isv + pk * ND);
        const float4* n4 = (const float4*)(nmv + pk * ND);
        float4 is0 = i4[0], is1 = i4[1], is2 = i4[2], is3 = i4[3];
        float4 nm0 = n4[0], nm1 = n4[1], nm2 = n4[2], nm3 = n4[3];
        const float c = cv[pk];

#pragma unroll
        for (int b = 0; b < BT; ++b) {
            const float4* xq = (const float4*)(&xg[b][rl][0]);
            float4 x0 = xq[0], x1 = xq[1], x2 = xq[2], x3 = xq[3];
            float acc = 0.f;
#define STEP(xx, ii, nn) { float z = fmaf(xx, ii, nn); acc = fmaf(z, z, acc); }
            STEP(x0.x, is0.x, nm0.x); STEP(x0.y, is0.y, nm0.y);
            STEP(x0.z, is0.z, nm0.z); STEP(x0.w, is0.w, nm0.w);
            STEP(x1.x, is1.x, nm1.x); STEP(x1.y, is1.y, nm1.y);
            STEP(x1.z, is1.z, nm1.z); STEP(x1.w, is1.w, nm1.w);
            STEP(x2.x, is2.x, nm2.x); STEP(x2.y, is2.y, nm2.y);
            STEP(x2.z, is2.z, nm2.z); STEP(x2.w, is2.w, nm2.w);
            STEP(x3.x, is3.x, nm3.x); STEP(x3.y, is3.y, nm3.y);
            STEP(x3.z, is3.z, nm3.z); STEP(x3.w, is3.w, nm3.w);
#undef STEP
            out[(size_t)(b0 + b) * (NR * NK) + r * NK + k] = fmaf(acc, -0.5f, c);
        }
    }
}

extern "C" void kernel_launch(void* const* d_in, const int* in_sizes, int n_in,
                              void* d_out, int out_size, void* d_ws, size_t ws_size,
                              hipStream_t stream) {
    const float* x       = (const float*)d_in[0];
    const int*   regions = (const int*)d_in[1];
    const float* means   = (const float*)d_in[2];
    const float* scales  = (const float*)d_in[3];
    float* out = (float*)d_out;

    float* w   = (float*)d_ws;
    float* isv = w;                       // [NR*NK*ND]
    float* nmv = w + NR * NK * ND;        // [NR*NK*ND]
    float* cv  = w + 2 * NR * NK * ND;    // [NR*NK]

    prep_kernel<<<dim3((NR * NK + 255) / 256), 256, 0, stream>>>(means, scales, isv, nmv, cv);

    dim3 grid(NB / BT, NR / RT);
    GaussianLayer_64003602645438_kernel<<<grid, 256, 0, stream>>>(x, regions, isv, nmv, cv, out);
}